// Round 11
// baseline (187.712 us; speedup 1.0000x reference)
//
#include <hip/hip_runtime.h>
#include <math.h>

// VectorQuantizer via MFMA: in [32,64,64,64] fp32 NCHW (C=D=64), w [512,64] fp32.
// R20: single-kernel fusion WITHOUT inter-block communication (R14's flag-spin
// failed because ws is re-poisoned every iteration). Each block redundantly
// converts the codebook per-chunk into its own LDS:
//  - per chunk: 512 threads = 64 codes x 8 granules = exactly one prep-unit
//    per thread (2x float4 load, ~70 VALU, 2x ds_write_b128, 3 shfl).
//  - depth-2 register pipeline: wA/wB alternate across unrolled chunk-pairs;
//    every W-load covered by >=1 compute phase (4 tiles). No reg moves.
//  - conversion math VERBATIM vq_prep (RNE hi/lo, same fmaf chain, same shfl
//    tree) -> wn bit-identical, B-fragments byte-identical to old wfrag layout.
//  - loss cell zeroed via 4-byte hipMemsetAsync (graph-safe, verified R14).
// Rationale: bench-kernel gap is ~69us with 2 dispatches vs ~55us with 1
// (R14 measured); prep+dispatch costs ~10-15us of bench, ~30% of kernel time.
// Tripwire: WRITE_SIZE must stay 32.8MB (spill detector, R15 lesson).
// K-loop / A-prep / argmin (fmed3, no setprio) / merge / fp64 re-rank /
// epilogues: verbatim R19 (best: 115.4us bench, absmax 1.2e-4).
typedef short bf16x8 __attribute__((ext_vector_type(8)));
typedef float f32x4 __attribute__((ext_vector_type(4)));

#define VQ_D 64
#define VQ_K 512
#define VQ_NQ 131072
#define VQ_TOTAL 8388608
#define TAU 8e-3f

__device__ __forceinline__ ushort bf16_rne(float f) {
    uint u = __builtin_bit_cast(uint, f);
    u += 0x7fffu + ((u >> 16) & 1u);
    return (ushort)(u >> 16);
}
__device__ __forceinline__ float bf16_to_f(ushort h) {
    uint u = ((uint)h) << 16;
    return __builtin_bit_cast(float, u);
}
// bf16-RNE leaving the result in the TOP 16 bits (for v_perm packing)
__device__ __forceinline__ uint rne_top(float r) {
    uint t = __builtin_bit_cast(uint, r);
    return t + 0x7fffu + ((t >> 16) & 1u);
}
// pack top16(a) as low ushort, top16(b) as high ushort: one v_perm_b32
__device__ __forceinline__ uint pack_hi16(uint a, uint b) {
    return __builtin_amdgcn_perm(b, a, 0x07060302u);
}

// ---- per-chunk codebook conversion (math verbatim vq_prep) ----
// tid -> (code-in-chunk = tid>>3, granule g = tid&7). Writes the 16KB chunk
// buffer in the exact layout the K-loop reads:
//   byte = s*4096 + region*1024 + (quad*16+col)*16, region = {bh0,bh1,bl0,bl1}
__device__ __forceinline__ void conv_chunk(float4 a, float4 b4, int tid, int chunk,
                                           char* buf, float* wn_lds) {
    const int ci = tid >> 3;          // code within chunk (0..63)
    const int g  = tid & 7;           // granule: d in [g*8, g*8+8)
    float v[8] = {a.x, a.y, a.z, a.w, b4.x, b4.y, b4.z, b4.w};
    ushort hi[8], lo[8];
    float nrm = 0.f;
#pragma unroll
    for (int j = 0; j < 8; ++j) {
        nrm = fmaf(v[j], v[j], nrm);
        hi[j] = bf16_rne(v[j]);
        lo[j] = bf16_rne(v[j] - bf16_to_f(hi[j]));
    }
    // sum ||.||^2 over the code's 8 granule-lanes (consecutive, same wave)
    nrm += __shfl_xor(nrm, 1, 64);
    nrm += __shfl_xor(nrm, 2, 64);
    nrm += __shfl_xor(nrm, 4, 64);
    if (g == 0) wn_lds[chunk * 64 + ci] = nrm;
    const int s = ci >> 4, col = ci & 15;
    const int quad = g & 3, fh = g >> 2;
    char* base = buf + s * 4096 + (quad * 16 + col) * 16;
    *(bf16x8*)(base + fh * 1024)        = *(bf16x8*)hi;   // bh{fh}
    *(bf16x8*)(base + 2048 + fh * 1024) = *(bf16x8*)lo;   // bl{fh}
}

__global__ __launch_bounds__(512, 8) void vq_fused(const float* __restrict__ in,
                                                   const float* __restrict__ w,
                                                   float* __restrict__ out) {
    __shared__ __align__(16) char bstage[2][16384];  // double-buffered B chunks
    __shared__ float wn_lds[VQ_K];
    __shared__ float xn_lds[128];
    __shared__ float best_lds[128], sec_lds[128];
    __shared__ int   bi_lds[128], si_lds[128];
    __shared__ double loss_lds[8];

    const int tid  = threadIdx.x;
    const int lane = tid & 63;
    const int wid  = tid >> 6;                 // 8 waves
    const int col  = lane & 15;
    const int quad = lane >> 4;
    const int n0  = blockIdx.x * 128;          // block's 128 queries (one image)
    const int b   = n0 >> 12;
    const int hw0 = n0 & 4095;
    const float* xg0 = in + (b << 18) + hw0;

    // ---- prologue: issue W(0), W(1) loads (covered by A-prep) ----
    const int wci = tid >> 3, wg = tid & 7;    // this thread's code/granule unit
    const float4* p0 = (const float4*)(w + (0 * 64 + wci) * VQ_D) + 2 * wg;
    float4 wa0 = p0[0], wa1 = p0[1];
    const float4* p1 = (const float4*)(w + (1 * 64 + wci) * VQ_D) + 2 * wg;
    float4 wb0 = p1[0], wb1 = p1[1];

    // ---- A fragments direct from global (x, bf16 hi/lo) + xnorm (R19 verbatim) ----
    // 16 queries per wave: query = wid*16 + col; A[m=col][k=quad*8+j].
    bf16x8 ah0, ah1, al0, al1;
    {
        const float* xq = xg0 + wid * 16 + col;
        float sx = 0.f;
        uint AH0[4], AL0[4], AH1[4], AL1[4];
#pragma unroll
        for (int m = 0; m < 4; ++m) {          // bf16 pair m: j = 2m, 2m+1
            float a0 = xq[(quad * 8 + 2 * m) << 12];          // kstep0: d in [0,32)
            float b0 = xq[(quad * 8 + 2 * m + 1) << 12];
            float a1 = xq[(32 + quad * 8 + 2 * m) << 12];     // kstep1: d in [32,64)
            float b1 = xq[(32 + quad * 8 + 2 * m + 1) << 12];
            sx = fmaf(a0, a0, sx); sx = fmaf(b0, b0, sx);
            sx = fmaf(a1, a1, sx); sx = fmaf(b1, b1, sx);
            uint ua0 = __builtin_bit_cast(uint, a0), ub0 = __builtin_bit_cast(uint, b0);
            uint ua1 = __builtin_bit_cast(uint, a1), ub1 = __builtin_bit_cast(uint, b1);
            AH0[m] = pack_hi16(ua0, ub0);
            AH1[m] = pack_hi16(ua1, ub1);
            float ha0 = __builtin_bit_cast(float, ua0 & 0xFFFF0000u);
            float hb0 = __builtin_bit_cast(float, ub0 & 0xFFFF0000u);
            float ha1 = __builtin_bit_cast(float, ua1 & 0xFFFF0000u);
            float hb1 = __builtin_bit_cast(float, ub1 & 0xFFFF0000u);
            AL0[m] = pack_hi16(rne_top(a0 - ha0), rne_top(b0 - hb0));
            AL1[m] = pack_hi16(rne_top(a1 - ha1), rne_top(b1 - hb1));
        }
        ah0 = *(bf16x8*)AH0; al0 = *(bf16x8*)AL0;
        ah1 = *(bf16x8*)AH1; al1 = *(bf16x8*)AL1;
        sx += __shfl_xor(sx, 16, 64);                   // sum the 4 quads
        sx += __shfl_xor(sx, 32, 64);
        if (quad == 0) xn_lds[wid * 16 + col] = sx;
    }

    // ---- convert chunk 0 into buf0 (W(0) latency covered by A-prep) ----
    conv_chunk(wa0, wa1, tid, 0, &bstage[0][0], wn_lds);
    __syncthreads();   // buf0 + wn(chunk0) + xn_lds ready; W(1) still in flight

    // ---- K-loop: 4 unrolled chunk-pairs; wA/wB alternate (no reg moves) ----
    float best[4], sec[4];
#pragma unroll
    for (int r = 0; r < 4; ++r) { best[r] = 3.0e38f; sec[r] = 3.0e38f; }

#define VQ_COMPUTE(T2BASE, BUF)                                                   \
    {                                                                             \
        _Pragma("unroll")                                                         \
        for (int s = 0; s < 4; ++s) {                                             \
            const int t2 = (T2BASE) + s;                                          \
            const char* rb = (BUF) + s * 4096 + lane * 16;                        \
            bf16x8 bh0 = *(const bf16x8*)(rb);                                    \
            bf16x8 bh1 = *(const bf16x8*)(rb + 1024);                             \
            bf16x8 bl0 = *(const bf16x8*)(rb + 2048);                             \
            bf16x8 bl1 = *(const bf16x8*)(rb + 3072);                             \
            const float wnv = wn_lds[t2 * 16 + col];                              \
            f32x4 acc = {0.f, 0.f, 0.f, 0.f};                                     \
            acc = __builtin_amdgcn_mfma_f32_16x16x32_bf16(ah0, bh0, acc, 0, 0, 0);\
            acc = __builtin_amdgcn_mfma_f32_16x16x32_bf16(ah1, bh1, acc, 0, 0, 0);\
            acc = __builtin_amdgcn_mfma_f32_16x16x32_bf16(ah0, bl0, acc, 0, 0, 0);\
            acc = __builtin_amdgcn_mfma_f32_16x16x32_bf16(ah1, bl1, acc, 0, 0, 0);\
            acc = __builtin_amdgcn_mfma_f32_16x16x32_bf16(al0, bh0, acc, 0, 0, 0);\
            acc = __builtin_amdgcn_mfma_f32_16x16x32_bf16(al1, bh1, acc, 0, 0, 0);\
            _Pragma("unroll")                                                     \
            for (int j = 0; j < 4; ++j) {                                         \
                float dist = fmaf(-2.f, acc[j], wnv);                             \
                uint u = (__builtin_bit_cast(uint, dist) & 0xFFFFFFE0u)           \
                       | ((uint)t2 & 0x1Fu);                                      \
                float key = __builtin_bit_cast(float, u);                         \
                sec[j]  = __builtin_amdgcn_fmed3f(best[j], sec[j], key);          \
                best[j] = fminf(best[j], key);                                    \
            }                                                                     \
        }                                                                         \
    }

#pragma unroll 1
    for (int i = 0; i < 4; ++i) {
        // chunks 2i (buf0, ready) and 2i+1 (convert now from wB)
        conv_chunk(wb0, wb1, tid, 2 * i + 1, &bstage[1][0], wn_lds);
        if (i < 3) {                        // issue W(2i+2) -> wA
            const float4* p = (const float4*)(w + ((2 * i + 2) * 64 + wci) * VQ_D) + 2 * wg;
            wa0 = p[0]; wa1 = p[1];
        }
        VQ_COMPUTE(4 * (2 * i), &bstage[0][0]);
        __syncthreads();   // buf1+wn(2i+1) visible; buf0 reads done
        if (i < 3) {
            conv_chunk(wa0, wa1, tid, 2 * i + 2, &bstage[0][0], wn_lds);
            const float4* p = (const float4*)(w + ((2 * i + 3) * 64 + wci) * VQ_D) + 2 * wg;
            wb0 = p[0]; wb1 = p[1];         // issue W(2i+3) -> wB
        }
        VQ_COMPUTE(4 * (2 * i + 1), &bstage[1][0]);
        __syncthreads();   // buf0+wn(2i+2) visible; buf1 reads done
    }
#undef VQ_COMPUTE

    // ---- unpack packed keys -> (dist_class, global code idx) (R19 verbatim) ----
    float bD[4], sD[4];
    int bI[4], sI[4];
#pragma unroll
    for (int r = 0; r < 4; ++r) {
        uint ub = __builtin_bit_cast(uint, best[r]);
        uint us = __builtin_bit_cast(uint, sec[r]);
        bI[r] = (int)(ub & 31u) * 16 + col;
        sI[r] = (int)(us & 31u) * 16 + col;
        bD[r] = __builtin_bit_cast(float, ub & 0xFFFFFFE0u);
        sD[r] = __builtin_bit_cast(float, us & 0xFFFFFFE0u);
    }

    // ---- merge across 16 col-lanes (R19 verbatim) ----
#pragma unroll
    for (int off = 1; off < 16; off <<= 1) {
#pragma unroll
        for (int r = 0; r < 4; ++r) {
            float ob = __shfl_xor(bD[r], off, 64);
            float os = __shfl_xor(sD[r], off, 64);
            int   oi = __shfl_xor(bI[r], off, 64);
            int   oc = __shfl_xor(sI[r], off, 64);
            bool oWins = (ob < bD[r]) || (ob == bD[r] && oi < bI[r]);
            float nb  = oWins ? ob    : bD[r];
            int   ni  = oWins ? oi    : bI[r];
            float c1  = oWins ? bD[r] : ob;      // loser's best
            int   ci1 = oWins ? bI[r] : oi;
            float c2  = oWins ? os    : sD[r];   // winner's second
            int   ci2 = oWins ? oc    : sI[r];
            bool c1w = (c1 < c2) || (c1 == c2 && ci1 < ci2);
            sD[r] = c1w ? c1  : c2;
            sI[r] = c1w ? ci1 : ci2;
            bD[r] = nb; bI[r] = ni;
        }
    }
    if (col == 0) {
#pragma unroll
        for (int r = 0; r < 4; ++r) {           // q in block = wid*16 + quad*4 + r
            const int q = wid * 16 + quad * 4 + r;
            best_lds[q] = bD[r]; sec_lds[q] = sD[r];
            bi_lds[q] = bI[r];   si_lds[q] = sI[r];
        }
    }
    __syncthreads();

    // ---- epilogue: fp64 near-tie re-rank, 4 lanes per query + loss (R19 verbatim) ----
    {
        const int q = tid >> 2, part = tid & 3;   // lanes 4k..4k+3 share query q
        float cb = best_lds[q], cs = sec_lds[q];
        int cbi = bi_lds[q], csi = si_lds[q];
        double chosen = (double)cb;
        if (cs - cb < TAU) {
            const float* wb  = w + cbi * VQ_D + part * 16;
            const float* ws2 = w + csi * VQ_D + part * 16;
            const float* xqp = xg0 + q;
            double nb = 0.0, dotb = 0.0, ns = 0.0, dots = 0.0;
#pragma unroll
            for (int d0 = 0; d0 < 16; ++d0) {
                const int d = part * 16 + d0;
                double xv = (double)xqp[d << 12];
                double wbv = (double)wb[d0], wsv = (double)ws2[d0];
                nb = fma(wbv, wbv, nb); dotb = fma(xv, wbv, dotb);
                ns = fma(wsv, wsv, ns); dots = fma(xv, wsv, dots);
            }
            // combine the 4 partials (butterfly within the 4-lane group)
#pragma unroll
            for (int off = 1; off < 4; off <<= 1) {
                nb   += __shfl_xor(nb,   off, 64);
                dotb += __shfl_xor(dotb, off, 64);
                ns   += __shfl_xor(ns,   off, 64);
                dots += __shfl_xor(dots, off, 64);
            }
            double db = nb - 2.0 * dotb, ds = ns - 2.0 * dots;
            if (ds < db || (ds == db && csi < cbi)) { cbi = csi; chosen = ds; }
            else                                    { chosen = db; }
        }
        if (part == 0) bi_lds[q] = cbi;
        double lq = (part == 0) ? ((double)xn_lds[q] + chosen) : 0.0;
#pragma unroll
        for (int off = 32; off > 0; off >>= 1)
            lq += __shfl_down(lq, off, 64);
        if (lane == 0) loss_lds[wid] = lq;
    }
    __syncthreads();
    if (tid == 0) {
        double s = 0.0;
#pragma unroll
        for (int wv = 0; wv < 8; ++wv) s += loss_lds[wv];
        atomicAdd(out + VQ_TOTAL, (float)(s * (1.0 / (double)VQ_TOTAL)));
    }

    // ---- cooperative quantized write: 4 threads/query (R19 verbatim) ----
    {
        const int q = tid & 127, quarter = tid >> 7;  // quarter: d in [16*quarter, +16)
        const float4* wrow = (const float4*)(w + bi_lds[q] * VQ_D) + quarter * 4;
        float* op = out + (b << 18) + hw0 + q;
#pragma unroll
        for (int u = 0; u < 4; ++u) {
            float4 v = wrow[u];
            const int d = quarter * 16 + 4 * u;
            op[(d + 0) << 12] = v.x;
            op[(d + 1) << 12] = v.y;
            op[(d + 2) << 12] = v.z;
            op[(d + 3) << 12] = v.w;
        }
    }
}

extern "C" void kernel_launch(void* const* d_in, const int* in_sizes, int n_in,
                              void* d_out, int out_size, void* d_ws, size_t ws_size,
                              hipStream_t stream) {
    const float* in = (const float*)d_in[0];
    const float* w  = (const float*)d_in[1];
    float* out = (float*)d_out;

    // zero the loss accumulator cell (stream-ordered; graph-capture safe)
    hipMemsetAsync(out + VQ_TOTAL, 0, 4, stream);
    vq_fused<<<VQ_NQ / 128, 512, 0, stream>>>(in, w, out);
}

// Round 12
// 175.086 us; speedup vs baseline: 1.0721x; 1.0721x over previous
//
#include <hip/hip_runtime.h>
#include <math.h>

// VectorQuantizer via MFMA: in [32,64,64,64] fp32 NCHW (C=D=64), w [512,64] fp32.
// R21: single-kernel fusion, R20's two defects fixed.
//  R20 diagnosis: (a) (512,8)=64-VGPR cap + deep wA/wB pipeline -> scratch spill
//  (WRITE 231MB, FETCH 197MB incl. L3-thrashed input re-reads); (b) conv write
//  addr had quad*256 (vanishes mod 128B bank period) -> 8-way conflict (7.3M).
//  Fixes:
//  - depth-1 W prefetch: one float4-pair (8 VGPRs) issued at loop top, consumed
//    after compute. Peak VGPR ~52-58 < 64 cap. Tripwire: WRITE_SIZE == 32.8MB.
//  - linear conversion mapping: tid -> (cs=tid>>7, cfh=(tid>>6)&1, cquad, ccol);
//    per-wave frag-write addr = const + lane*16 (conflict-free, = K-loop read
//    pattern). Tripwire: SQ_LDS_BANK_CONFLICT ~ 0.
//  - wn as two half-partials wn_a/wn_b (fh crosses the wave bit); shfl tree
//    re-associated exactly as vq_prep ((g0+g1)+(g2+g3) per half, halves added
//    at use) -> wn bit-identical -> absmax must stay 1.2e-4.
//  - loss cell zeroed via hipMemsetAsync (graph-safe, verified R14/R20).
// K-loop / A-prep / argmin (fmed3, no setprio) / merge / fp64 re-rank /
// epilogues: verbatim R19 (best: 115.4us bench, kernel ~46.5us).
typedef short bf16x8 __attribute__((ext_vector_type(8)));
typedef float f32x4 __attribute__((ext_vector_type(4)));

#define VQ_D 64
#define VQ_K 512
#define VQ_NQ 131072
#define VQ_TOTAL 8388608
#define TAU 8e-3f

__device__ __forceinline__ ushort bf16_rne(float f) {
    uint u = __builtin_bit_cast(uint, f);
    u += 0x7fffu + ((u >> 16) & 1u);
    return (ushort)(u >> 16);
}
__device__ __forceinline__ float bf16_to_f(ushort h) {
    uint u = ((uint)h) << 16;
    return __builtin_bit_cast(float, u);
}
// bf16-RNE leaving the result in the TOP 16 bits (for v_perm packing)
__device__ __forceinline__ uint rne_top(float r) {
    uint t = __builtin_bit_cast(uint, r);
    return t + 0x7fffu + ((t >> 16) & 1u);
}
// pack top16(a) as low ushort, top16(b) as high ushort: one v_perm_b32
__device__ __forceinline__ uint pack_hi16(uint a, uint b) {
    return __builtin_amdgcn_perm(b, a, 0x07060302u);
}

__global__ __launch_bounds__(512, 8) void vq_fused(const float* __restrict__ in,
                                                   const float* __restrict__ w,
                                                   float* __restrict__ out) {
    __shared__ __align__(16) char bstage[2][16384];  // double-buffered frag chunks
    __shared__ float wn_a[VQ_K], wn_b[VQ_K];         // per-fh norm partials
    __shared__ float xn_lds[128];
    __shared__ float best_lds[128], sec_lds[128];
    __shared__ int   bi_lds[128], si_lds[128];
    __shared__ double loss_lds[8];

    const int tid  = threadIdx.x;
    const int lane = tid & 63;
    const int wid  = tid >> 6;                 // 8 waves
    const int col  = lane & 15;
    const int quad = lane >> 4;
    const int n0  = blockIdx.x * 128;          // block's 128 queries (one image)
    const int b   = n0 >> 12;
    const int hw0 = n0 & 4095;
    const float* xg0 = in + (b << 18) + hw0;

    // ---- conversion role: tile cs, frag-half cfh, quad/col == lane bits ----
    // thread converts code (cs*16+col) granule (cfh*4+quad) of each chunk.
    const int cs  = tid >> 7;                  // tile within chunk (0..3)
    const int cfh = (tid >> 6) & 1;            // fragment half (wave bit)
    // W float offset of this thread's 8-value granule within a chunk:
    const int cgOff = (cs * 16 + col) * 64 + (cfh * 4 + quad) * 8;
    float* wn_half = cfh ? wn_b : wn_a;

    // frag-write base: per-wave addr = cs*4096 + cfh*1024 + lane*16 (LINEAR)
    char* const cwbase0 = &bstage[0][0] + cs * 4096 + cfh * 1024 + lane * 16;
    char* const cwbase1 = &bstage[1][0] + cs * 4096 + cfh * 1024 + lane * 16;

#define VQ_CONV(A4, B4, CHUNK, CWBASE)                                            \
    {                                                                             \
        float v[8] = {(A4).x, (A4).y, (A4).z, (A4).w,                             \
                      (B4).x, (B4).y, (B4).z, (B4).w};                            \
        ushort hi[8], lo[8];                                                      \
        float nrm = 0.f;                                                          \
        _Pragma("unroll")                                                         \
        for (int j = 0; j < 8; ++j) {                                             \
            nrm = fmaf(v[j], v[j], nrm);                                          \
            hi[j] = bf16_rne(v[j]);                                               \
            lo[j] = bf16_rne(v[j] - bf16_to_f(hi[j]));                            \
        }                                                                         \
        nrm += __shfl_xor(nrm, 16, 64);   /* (g0+g1),(g2+g3) pairing */           \
        nrm += __shfl_xor(nrm, 32, 64);   /* ((g0+g1)+(g2+g3)) per half */        \
        if (quad == 0) wn_half[(CHUNK) * 64 + cs * 16 + col] = nrm;               \
        *(bf16x8*)(CWBASE)        = *(bf16x8*)hi;   /* bh{cfh} */                 \
        *(bf16x8*)((CWBASE) + 2048) = *(bf16x8*)lo; /* bl{cfh} */                 \
    }

    // ---- prologue: issue W(0) loads (covered by A-prep) ----
    float4 wr0, wr1;
    {
        const float4* p = (const float4*)(w + cgOff);
        wr0 = p[0]; wr1 = p[1];
    }

    // ---- A fragments direct from global (x, bf16 hi/lo) + xnorm (R19 verbatim) ----
    bf16x8 ah0, ah1, al0, al1;
    {
        const float* xq = xg0 + wid * 16 + col;
        float sx = 0.f;
        uint AH0[4], AL0[4], AH1[4], AL1[4];
#pragma unroll
        for (int m = 0; m < 4; ++m) {          // bf16 pair m: j = 2m, 2m+1
            float a0 = xq[(quad * 8 + 2 * m) << 12];          // kstep0: d in [0,32)
            float b0 = xq[(quad * 8 + 2 * m + 1) << 12];
            float a1 = xq[(32 + quad * 8 + 2 * m) << 12];     // kstep1: d in [32,64)
            float b1 = xq[(32 + quad * 8 + 2 * m + 1) << 12];
            sx = fmaf(a0, a0, sx); sx = fmaf(b0, b0, sx);
            sx = fmaf(a1, a1, sx); sx = fmaf(b1, b1, sx);
            uint ua0 = __builtin_bit_cast(uint, a0), ub0 = __builtin_bit_cast(uint, b0);
            uint ua1 = __builtin_bit_cast(uint, a1), ub1 = __builtin_bit_cast(uint, b1);
            AH0[m] = pack_hi16(ua0, ub0);
            AH1[m] = pack_hi16(ua1, ub1);
            float ha0 = __builtin_bit_cast(float, ua0 & 0xFFFF0000u);
            float hb0 = __builtin_bit_cast(float, ub0 & 0xFFFF0000u);
            float ha1 = __builtin_bit_cast(float, ua1 & 0xFFFF0000u);
            float hb1 = __builtin_bit_cast(float, ub1 & 0xFFFF0000u);
            AL0[m] = pack_hi16(rne_top(a0 - ha0), rne_top(b0 - hb0));
            AL1[m] = pack_hi16(rne_top(a1 - ha1), rne_top(b1 - hb1));
        }
        ah0 = *(bf16x8*)AH0; al0 = *(bf16x8*)AL0;
        ah1 = *(bf16x8*)AH1; al1 = *(bf16x8*)AL1;
        sx += __shfl_xor(sx, 16, 64);                   // sum the 4 quads
        sx += __shfl_xor(sx, 32, 64);
        if (quad == 0) xn_lds[wid * 16 + col] = sx;
    }

    // ---- convert chunk 0 (W(0) latency covered by A-prep) ----
    VQ_CONV(wr0, wr1, 0, cwbase0);
    __syncthreads();   // chunk-0 frags + wn partials + xn_lds visible

    // ---- K-loop: compute chunk c; then convert chunk c+1 (loaded at loop top) ----
    float best[4], sec[4];
#pragma unroll
    for (int r = 0; r < 4; ++r) { best[r] = 3.0e38f; sec[r] = 3.0e38f; }

#pragma unroll 1
    for (int c = 0; c < 8; ++c) {
        float4 nx0, nx1;
        if (c < 7) {                            // issue W(c+1); consumed post-compute
            const float4* p = (const float4*)(w + (c + 1) * 4096 + cgOff);
            nx0 = p[0]; nx1 = p[1];
        }
        const char* bcur = &bstage[c & 1][0];
#pragma unroll
        for (int s = 0; s < 4; ++s) {           // four 16-code tiles per chunk
            const int t2 = 4 * c + s;
            const char* rb = bcur + s * 4096 + lane * 16;
            bf16x8 bh0 = *(const bf16x8*)(rb);
            bf16x8 bh1 = *(const bf16x8*)(rb + 1024);
            bf16x8 bl0 = *(const bf16x8*)(rb + 2048);
            bf16x8 bl1 = *(const bf16x8*)(rb + 3072);
            const float wnv = wn_a[t2 * 16 + col] + wn_b[t2 * 16 + col];
            f32x4 acc = {0.f, 0.f, 0.f, 0.f};
            acc = __builtin_amdgcn_mfma_f32_16x16x32_bf16(ah0, bh0, acc, 0, 0, 0);
            acc = __builtin_amdgcn_mfma_f32_16x16x32_bf16(ah1, bh1, acc, 0, 0, 0);
            acc = __builtin_amdgcn_mfma_f32_16x16x32_bf16(ah0, bl0, acc, 0, 0, 0);
            acc = __builtin_amdgcn_mfma_f32_16x16x32_bf16(ah1, bl1, acc, 0, 0, 0);
            acc = __builtin_amdgcn_mfma_f32_16x16x32_bf16(al0, bh0, acc, 0, 0, 0);
            acc = __builtin_amdgcn_mfma_f32_16x16x32_bf16(al1, bh1, acc, 0, 0, 0);
#pragma unroll
            for (int j = 0; j < 4; ++j) {       // C: row(query)=quad*4+j, col=code
                float dist = fmaf(-2.f, acc[j], wnv);
                uint u = (__builtin_bit_cast(uint, dist) & 0xFFFFFFE0u)
                       | ((uint)t2 & 0x1Fu);    // fuses to v_bfi_b32
                float key = __builtin_bit_cast(float, u);
                sec[j]  = __builtin_amdgcn_fmed3f(best[j], sec[j], key);
                best[j] = fminf(best[j], key);
            }
        }
        if (c < 7) {
            // buffer (c+1)&1 was last read in iter c-1 (pre-barrier) -> safe.
            VQ_CONV(nx0, nx1, c + 1, ((c + 1) & 1) ? cwbase1 : cwbase0);
        }
        __syncthreads();   // frag writes visible; chunk-c reads done
    }
#undef VQ_CONV

    // ---- unpack packed keys -> (dist_class, global code idx) (R19 verbatim) ----
    float bD[4], sD[4];
    int bI[4], sI[4];
#pragma unroll
    for (int r = 0; r < 4; ++r) {
        uint ub = __builtin_bit_cast(uint, best[r]);
        uint us = __builtin_bit_cast(uint, sec[r]);
        bI[r] = (int)(ub & 31u) * 16 + col;
        sI[r] = (int)(us & 31u) * 16 + col;
        bD[r] = __builtin_bit_cast(float, ub & 0xFFFFFFE0u);
        sD[r] = __builtin_bit_cast(float, us & 0xFFFFFFE0u);
    }

    // ---- merge across 16 col-lanes (R19 verbatim) ----
#pragma unroll
    for (int off = 1; off < 16; off <<= 1) {
#pragma unroll
        for (int r = 0; r < 4; ++r) {
            float ob = __shfl_xor(bD[r], off, 64);
            float os = __shfl_xor(sD[r], off, 64);
            int   oi = __shfl_xor(bI[r], off, 64);
            int   oc = __shfl_xor(sI[r], off, 64);
            bool oWins = (ob < bD[r]) || (ob == bD[r] && oi < bI[r]);
            float nb  = oWins ? ob    : bD[r];
            int   ni  = oWins ? oi    : bI[r];
            float c1  = oWins ? bD[r] : ob;      // loser's best
            int   ci1 = oWins ? bI[r] : oi;
            float c2  = oWins ? os    : sD[r];   // winner's second
            int   ci2 = oWins ? oc    : sI[r];
            bool c1w = (c1 < c2) || (c1 == c2 && ci1 < ci2);
            sD[r] = c1w ? c1  : c2;
            sI[r] = c1w ? ci1 : ci2;
            bD[r] = nb; bI[r] = ni;
        }
    }
    if (col == 0) {
#pragma unroll
        for (int r = 0; r < 4; ++r) {           // q in block = wid*16 + quad*4 + r
            const int q = wid * 16 + quad * 4 + r;
            best_lds[q] = bD[r]; sec_lds[q] = sD[r];
            bi_lds[q] = bI[r];   si_lds[q] = sI[r];
        }
    }
    __syncthreads();

    // ---- epilogue: fp64 near-tie re-rank, 4 lanes per query + loss (R19 verbatim) ----
    {
        const int q = tid >> 2, part = tid & 3;   // lanes 4k..4k+3 share query q
        float cb = best_lds[q], cs2 = sec_lds[q];
        int cbi = bi_lds[q], csi = si_lds[q];
        double chosen = (double)cb;
        if (cs2 - cb < TAU) {
            const float* wb  = w + cbi * VQ_D + part * 16;
            const float* ws2 = w + csi * VQ_D + part * 16;
            const float* xqp = xg0 + q;
            double nb = 0.0, dotb = 0.0, ns = 0.0, dots = 0.0;
#pragma unroll
            for (int d0 = 0; d0 < 16; ++d0) {
                const int d = part * 16 + d0;
                double xv = (double)xqp[d << 12];
                double wbv = (double)wb[d0], wsv = (double)ws2[d0];
                nb = fma(wbv, wbv, nb); dotb = fma(xv, wbv, dotb);
                ns = fma(wsv, wsv, ns); dots = fma(xv, wsv, dots);
            }
            // combine the 4 partials (butterfly within the 4-lane group)
#pragma unroll
            for (int off = 1; off < 4; off <<= 1) {
                nb   += __shfl_xor(nb,   off, 64);
                dotb += __shfl_xor(dotb, off, 64);
                ns   += __shfl_xor(ns,   off, 64);
                dots += __shfl_xor(dots, off, 64);
            }
            double db = nb - 2.0 * dotb, ds = ns - 2.0 * dots;
            if (ds < db || (ds == db && csi < cbi)) { cbi = csi; chosen = ds; }
            else                                    { chosen = db; }
        }
        if (part == 0) bi_lds[q] = cbi;
        double lq = (part == 0) ? ((double)xn_lds[q] + chosen) : 0.0;
#pragma unroll
        for (int off = 32; off > 0; off >>= 1)
            lq += __shfl_down(lq, off, 64);
        if (lane == 0) loss_lds[wid] = lq;
    }
    __syncthreads();
    if (tid == 0) {
        double s = 0.0;
#pragma unroll
        for (int wv = 0; wv < 8; ++wv) s += loss_lds[wv];
        atomicAdd(out + VQ_TOTAL, (float)(s * (1.0 / (double)VQ_TOTAL)));
    }

    // ---- cooperative quantized write: 4 threads/query (R19 verbatim) ----
    {
        const int q = tid & 127, quarter = tid >> 7;  // quarter: d in [16*quarter, +16)
        const float4* wrow = (const float4*)(w + bi_lds[q] * VQ_D) + quarter * 4;
        float* op = out + (b << 18) + hw0 + q;
#pragma unroll
        for (int u = 0; u < 4; ++u) {
            float4 v = wrow[u];
            const int d = quarter * 16 + 4 * u;
            op[(d + 0) << 12] = v.x;
            op[(d + 1) << 12] = v.y;
            op[(d + 2) << 12] = v.z;
            op[(d + 3) << 12] = v.w;
        }
    }
}

extern "C" void kernel_launch(void* const* d_in, const int* in_sizes, int n_in,
                              void* d_out, int out_size, void* d_ws, size_t ws_size,
                              hipStream_t stream) {
    const float* in = (const float*)d_in[0];
    const float* w  = (const float*)d_in[1];
    float* out = (float*)d_out;

    // zero the loss accumulator cell (stream-ordered; graph-capture safe)
    hipMemsetAsync(out + VQ_TOTAL, 0, 4, stream);
    vq_fused<<<VQ_NQ / 128, 512, 0, stream>>>(in, w, out);
}

// Round 13
// 139.572 us; speedup vs baseline: 1.3449x; 1.2544x over previous
//
#include <hip/hip_runtime.h>
#include <math.h>

// VectorQuantizer via MFMA: in [32,64,64,64] fp32 NCHW (C=D=64), w [512,64] fp32.
// R22 = R21 with ONE change: __launch_bounds__(512, 8) -> (512, 6).
//  R21 diagnosis: bank conflicts fixed (7.3M->0), correctness verified
//  (absmax 1.2e-4), but FETCH/WRITE 169/181MB = symmetric ~150MB excess =
//  W-prefetch float4s spilled across the compute phase. Demand ~73 VGPR vs
//  64 cap at (512,8). (512,6) => 84-VGPR budget >= demand -> no spill.
//  Cost: 3 blocks/CU (75% occ cap) vs 4 -- R19 only measured 56% anyway.
//  Lesson: dispatch VGPR_Count does NOT reveal spill (32-48 reported while
//  spilling in R15/R20/R21); the tripwire is symmetric FETCH/WRITE inflation.
// Decision rule: WRITE==32.8MB & bench<112 -> keep; else revert R19 = floor.
// K-loop / A-prep / conversion / argmin / merge / fp64 re-rank / epilogues:
// verbatim R21 (semantics-verified).
typedef short bf16x8 __attribute__((ext_vector_type(8)));
typedef float f32x4 __attribute__((ext_vector_type(4)));

#define VQ_D 64
#define VQ_K 512
#define VQ_NQ 131072
#define VQ_TOTAL 8388608
#define TAU 8e-3f

__device__ __forceinline__ ushort bf16_rne(float f) {
    uint u = __builtin_bit_cast(uint, f);
    u += 0x7fffu + ((u >> 16) & 1u);
    return (ushort)(u >> 16);
}
__device__ __forceinline__ float bf16_to_f(ushort h) {
    uint u = ((uint)h) << 16;
    return __builtin_bit_cast(float, u);
}
// bf16-RNE leaving the result in the TOP 16 bits (for v_perm packing)
__device__ __forceinline__ uint rne_top(float r) {
    uint t = __builtin_bit_cast(uint, r);
    return t + 0x7fffu + ((t >> 16) & 1u);
}
// pack top16(a) as low ushort, top16(b) as high ushort: one v_perm_b32
__device__ __forceinline__ uint pack_hi16(uint a, uint b) {
    return __builtin_amdgcn_perm(b, a, 0x07060302u);
}

__global__ __launch_bounds__(512, 6) void vq_fused(const float* __restrict__ in,
                                                   const float* __restrict__ w,
                                                   float* __restrict__ out) {
    __shared__ __align__(16) char bstage[2][16384];  // double-buffered frag chunks
    __shared__ float wn_a[VQ_K], wn_b[VQ_K];         // per-fh norm partials
    __shared__ float xn_lds[128];
    __shared__ float best_lds[128], sec_lds[128];
    __shared__ int   bi_lds[128], si_lds[128];
    __shared__ double loss_lds[8];

    const int tid  = threadIdx.x;
    const int lane = tid & 63;
    const int wid  = tid >> 6;                 // 8 waves
    const int col  = lane & 15;
    const int quad = lane >> 4;
    const int n0  = blockIdx.x * 128;          // block's 128 queries (one image)
    const int b   = n0 >> 12;
    const int hw0 = n0 & 4095;
    const float* xg0 = in + (b << 18) + hw0;

    // ---- conversion role: tile cs, frag-half cfh, quad/col == lane bits ----
    // thread converts code (cs*16+col) granule (cfh*4+quad) of each chunk.
    const int cs  = tid >> 7;                  // tile within chunk (0..3)
    const int cfh = (tid >> 6) & 1;            // fragment half (wave bit)
    // W float offset of this thread's 8-value granule within a chunk:
    const int cgOff = (cs * 16 + col) * 64 + (cfh * 4 + quad) * 8;
    float* wn_half = cfh ? wn_b : wn_a;

    // frag-write base: per-wave addr = cs*4096 + cfh*1024 + lane*16 (LINEAR)
    char* const cwbase0 = &bstage[0][0] + cs * 4096 + cfh * 1024 + lane * 16;
    char* const cwbase1 = &bstage[1][0] + cs * 4096 + cfh * 1024 + lane * 16;

#define VQ_CONV(A4, B4, CHUNK, CWBASE)                                            \
    {                                                                             \
        float v[8] = {(A4).x, (A4).y, (A4).z, (A4).w,                             \
                      (B4).x, (B4).y, (B4).z, (B4).w};                            \
        ushort hi[8], lo[8];                                                      \
        float nrm = 0.f;                                                          \
        _Pragma("unroll")                                                         \
        for (int j = 0; j < 8; ++j) {                                             \
            nrm = fmaf(v[j], v[j], nrm);                                          \
            hi[j] = bf16_rne(v[j]);                                               \
            lo[j] = bf16_rne(v[j] - bf16_to_f(hi[j]));                            \
        }                                                                         \
        nrm += __shfl_xor(nrm, 16, 64);   /* (g0+g1),(g2+g3) pairing */           \
        nrm += __shfl_xor(nrm, 32, 64);   /* ((g0+g1)+(g2+g3)) per half */        \
        if (quad == 0) wn_half[(CHUNK) * 64 + cs * 16 + col] = nrm;               \
        *(bf16x8*)(CWBASE)        = *(bf16x8*)hi;   /* bh{cfh} */                 \
        *(bf16x8*)((CWBASE) + 2048) = *(bf16x8*)lo; /* bl{cfh} */                 \
    }

    // ---- prologue: issue W(0) loads (covered by A-prep) ----
    float4 wr0, wr1;
    {
        const float4* p = (const float4*)(w + cgOff);
        wr0 = p[0]; wr1 = p[1];
    }

    // ---- A fragments direct from global (x, bf16 hi/lo) + xnorm (R19 verbatim) ----
    bf16x8 ah0, ah1, al0, al1;
    {
        const float* xq = xg0 + wid * 16 + col;
        float sx = 0.f;
        uint AH0[4], AL0[4], AH1[4], AL1[4];
#pragma unroll
        for (int m = 0; m < 4; ++m) {          // bf16 pair m: j = 2m, 2m+1
            float a0 = xq[(quad * 8 + 2 * m) << 12];          // kstep0: d in [0,32)
            float b0 = xq[(quad * 8 + 2 * m + 1) << 12];
            float a1 = xq[(32 + quad * 8 + 2 * m) << 12];     // kstep1: d in [32,64)
            float b1 = xq[(32 + quad * 8 + 2 * m + 1) << 12];
            sx = fmaf(a0, a0, sx); sx = fmaf(b0, b0, sx);
            sx = fmaf(a1, a1, sx); sx = fmaf(b1, b1, sx);
            uint ua0 = __builtin_bit_cast(uint, a0), ub0 = __builtin_bit_cast(uint, b0);
            uint ua1 = __builtin_bit_cast(uint, a1), ub1 = __builtin_bit_cast(uint, b1);
            AH0[m] = pack_hi16(ua0, ub0);
            AH1[m] = pack_hi16(ua1, ub1);
            float ha0 = __builtin_bit_cast(float, ua0 & 0xFFFF0000u);
            float hb0 = __builtin_bit_cast(float, ub0 & 0xFFFF0000u);
            float ha1 = __builtin_bit_cast(float, ua1 & 0xFFFF0000u);
            float hb1 = __builtin_bit_cast(float, ub1 & 0xFFFF0000u);
            AL0[m] = pack_hi16(rne_top(a0 - ha0), rne_top(b0 - hb0));
            AL1[m] = pack_hi16(rne_top(a1 - ha1), rne_top(b1 - hb1));
        }
        ah0 = *(bf16x8*)AH0; al0 = *(bf16x8*)AL0;
        ah1 = *(bf16x8*)AH1; al1 = *(bf16x8*)AL1;
        sx += __shfl_xor(sx, 16, 64);                   // sum the 4 quads
        sx += __shfl_xor(sx, 32, 64);
        if (quad == 0) xn_lds[wid * 16 + col] = sx;
    }

    // ---- convert chunk 0 (W(0) latency covered by A-prep) ----
    VQ_CONV(wr0, wr1, 0, cwbase0);
    __syncthreads();   // chunk-0 frags + wn partials + xn_lds visible

    // ---- K-loop: compute chunk c; then convert chunk c+1 (loaded at loop top) ----
    float best[4], sec[4];
#pragma unroll
    for (int r = 0; r < 4; ++r) { best[r] = 3.0e38f; sec[r] = 3.0e38f; }

#pragma unroll 1
    for (int c = 0; c < 8; ++c) {
        float4 nx0, nx1;
        if (c < 7) {                            // issue W(c+1); consumed post-compute
            const float4* p = (const float4*)(w + (c + 1) * 4096 + cgOff);
            nx0 = p[0]; nx1 = p[1];
        }
        const char* bcur = &bstage[c & 1][0];
#pragma unroll
        for (int s = 0; s < 4; ++s) {           // four 16-code tiles per chunk
            const int t2 = 4 * c + s;
            const char* rb = bcur + s * 4096 + lane * 16;
            bf16x8 bh0 = *(const bf16x8*)(rb);
            bf16x8 bh1 = *(const bf16x8*)(rb + 1024);
            bf16x8 bl0 = *(const bf16x8*)(rb + 2048);
            bf16x8 bl1 = *(const bf16x8*)(rb + 3072);
            const float wnv = wn_a[t2 * 16 + col] + wn_b[t2 * 16 + col];
            f32x4 acc = {0.f, 0.f, 0.f, 0.f};
            acc = __builtin_amdgcn_mfma_f32_16x16x32_bf16(ah0, bh0, acc, 0, 0, 0);
            acc = __builtin_amdgcn_mfma_f32_16x16x32_bf16(ah1, bh1, acc, 0, 0, 0);
            acc = __builtin_amdgcn_mfma_f32_16x16x32_bf16(ah0, bl0, acc, 0, 0, 0);
            acc = __builtin_amdgcn_mfma_f32_16x16x32_bf16(ah1, bl1, acc, 0, 0, 0);
            acc = __builtin_amdgcn_mfma_f32_16x16x32_bf16(al0, bh0, acc, 0, 0, 0);
            acc = __builtin_amdgcn_mfma_f32_16x16x32_bf16(al1, bh1, acc, 0, 0, 0);
#pragma unroll
            for (int j = 0; j < 4; ++j) {       // C: row(query)=quad*4+j, col=code
                float dist = fmaf(-2.f, acc[j], wnv);
                uint u = (__builtin_bit_cast(uint, dist) & 0xFFFFFFE0u)
                       | ((uint)t2 & 0x1Fu);    // fuses to v_bfi_b32
                float key = __builtin_bit_cast(float, u);
                sec[j]  = __builtin_amdgcn_fmed3f(best[j], sec[j], key);
                best[j] = fminf(best[j], key);
            }
        }
        if (c < 7) {
            // buffer (c+1)&1 was last read in iter c-1 (pre-barrier) -> safe.
            VQ_CONV(nx0, nx1, c + 1, ((c + 1) & 1) ? cwbase1 : cwbase0);
        }
        __syncthreads();   // frag writes visible; chunk-c reads done
    }
#undef VQ_CONV

    // ---- unpack packed keys -> (dist_class, global code idx) (R19 verbatim) ----
    float bD[4], sD[4];
    int bI[4], sI[4];
#pragma unroll
    for (int r = 0; r < 4; ++r) {
        uint ub = __builtin_bit_cast(uint, best[r]);
        uint us = __builtin_bit_cast(uint, sec[r]);
        bI[r] = (int)(ub & 31u) * 16 + col;
        sI[r] = (int)(us & 31u) * 16 + col;
        bD[r] = __builtin_bit_cast(float, ub & 0xFFFFFFE0u);
        sD[r] = __builtin_bit_cast(float, us & 0xFFFFFFE0u);
    }

    // ---- merge across 16 col-lanes (R19 verbatim) ----
#pragma unroll
    for (int off = 1; off < 16; off <<= 1) {
#pragma unroll
        for (int r = 0; r < 4; ++r) {
            float ob = __shfl_xor(bD[r], off, 64);
            float os = __shfl_xor(sD[r], off, 64);
            int   oi = __shfl_xor(bI[r], off, 64);
            int   oc = __shfl_xor(sI[r], off, 64);
            bool oWins = (ob < bD[r]) || (ob == bD[r] && oi < bI[r]);
            float nb  = oWins ? ob    : bD[r];
            int   ni  = oWins ? oi    : bI[r];
            float c1  = oWins ? bD[r] : ob;      // loser's best
            int   ci1 = oWins ? bI[r] : oi;
            float c2  = oWins ? os    : sD[r];   // winner's second
            int   ci2 = oWins ? oc    : sI[r];
            bool c1w = (c1 < c2) || (c1 == c2 && ci1 < ci2);
            sD[r] = c1w ? c1  : c2;
            sI[r] = c1w ? ci1 : ci2;
            bD[r] = nb; bI[r] = ni;
        }
    }
    if (col == 0) {
#pragma unroll
        for (int r = 0; r < 4; ++r) {           // q in block = wid*16 + quad*4 + r
            const int q = wid * 16 + quad * 4 + r;
            best_lds[q] = bD[r]; sec_lds[q] = sD[r];
            bi_lds[q] = bI[r];   si_lds[q] = sI[r];
        }
    }
    __syncthreads();

    // ---- epilogue: fp64 near-tie re-rank, 4 lanes per query + loss (R19 verbatim) ----
    {
        const int q = tid >> 2, part = tid & 3;   // lanes 4k..4k+3 share query q
        float cb = best_lds[q], cs2 = sec_lds[q];
        int cbi = bi_lds[q], csi = si_lds[q];
        double chosen = (double)cb;
        if (cs2 - cb < TAU) {
            const float* wb  = w + cbi * VQ_D + part * 16;
            const float* ws2 = w + csi * VQ_D + part * 16;
            const float* xqp = xg0 + q;
            double nb = 0.0, dotb = 0.0, ns = 0.0, dots = 0.0;
#pragma unroll
            for (int d0 = 0; d0 < 16; ++d0) {
                const int d = part * 16 + d0;
                double xv = (double)xqp[d << 12];
                double wbv = (double)wb[d0], wsv = (double)ws2[d0];
                nb = fma(wbv, wbv, nb); dotb = fma(xv, wbv, dotb);
                ns = fma(wsv, wsv, ns); dots = fma(xv, wsv, dots);
            }
            // combine the 4 partials (butterfly within the 4-lane group)
#pragma unroll
            for (int off = 1; off < 4; off <<= 1) {
                nb   += __shfl_xor(nb,   off, 64);
                dotb += __shfl_xor(dotb, off, 64);
                ns   += __shfl_xor(ns,   off, 64);
                dots += __shfl_xor(dots, off, 64);
            }
            double db = nb - 2.0 * dotb, ds = ns - 2.0 * dots;
            if (ds < db || (ds == db && csi < cbi)) { cbi = csi; chosen = ds; }
            else                                    { chosen = db; }
        }
        if (part == 0) bi_lds[q] = cbi;
        double lq = (part == 0) ? ((double)xn_lds[q] + chosen) : 0.0;
#pragma unroll
        for (int off = 32; off > 0; off >>= 1)
            lq += __shfl_down(lq, off, 64);
        if (lane == 0) loss_lds[wid] = lq;
    }
    __syncthreads();
    if (tid == 0) {
        double s = 0.0;
#pragma unroll
        for (int wv = 0; wv < 8; ++wv) s += loss_lds[wv];
        atomicAdd(out + VQ_TOTAL, (float)(s * (1.0 / (double)VQ_TOTAL)));
    }

    // ---- cooperative quantized write: 4 threads/query (R19 verbatim) ----
    {
        const int q = tid & 127, quarter = tid >> 7;  // quarter: d in [16*quarter, +16)
        const float4* wrow = (const float4*)(w + bi_lds[q] * VQ_D) + quarter * 4;
        float* op = out + (b << 18) + hw0 + q;
#pragma unroll
        for (int u = 0; u < 4; ++u) {
            float4 v = wrow[u];
            const int d = quarter * 16 + 4 * u;
            op[(d + 0) << 12] = v.x;
            op[(d + 1) << 12] = v.y;
            op[(d + 2) << 12] = v.z;
            op[(d + 3) << 12] = v.w;
        }
    }
}

extern "C" void kernel_launch(void* const* d_in, const int* in_sizes, int n_in,
                              void* d_out, int out_size, void* d_ws, size_t ws_size,
                              hipStream_t stream) {
    const float* in = (const float*)d_in[0];
    const float* w  = (const float*)d_in[1];
    float* out = (float*)d_out;

    // zero the loss accumulator cell (stream-ordered; graph-capture safe)
    hipMemsetAsync(out + VQ_TOTAL, 0, 4, stream);
    vq_fused<<<VQ_NQ / 128, 512, 0, stream>>>(in, w, out);
}

// Round 14
// 115.785 us; speedup vs baseline: 1.6212x; 1.2054x over previous
//
#include <hip/hip_runtime.h>
#include <math.h>

// VectorQuantizer via MFMA: in [32,64,64,64] fp32 NCHW (C=D=64), w [512,64] fp32.
// R23 = R19 restored verbatim (session best: bench 115.4us, kernel ~46.5us).
// Fusion line closed: R14 (flag-spin, 288us), R20 (spill+bank-conflict, 119us),
// R21 (spill, 105us), R22 (residual spill, 70.5us) -- all lose more in-kernel
// than the ~14us the second dispatch costs outside it.
// Lever ledger (all isolated on HW): staging +11% (R10), occupancy +25% (R11),
// VALU diet +5% (R13), fmed3/setprio +3% (R19); vmcnt pipeline null (R12);
// chunk-size -6% (R17); LDS-volume cuts -5..19% (R16/R18); fusion -52%..-6x.
// R19 counters: VALU 43%, MFMA 21%, HBM 13.5%, occ 56%, conflicts 0 -- no
// saturated pipe; residual is distributed dependency latency. 4 independent
// barrier-groups/CU covering each other's stalls beats every volume/pipeline
// trade attempted. Practical floor for this decomposition.
typedef short bf16x8 __attribute__((ext_vector_type(8)));
typedef float f32x4 __attribute__((ext_vector_type(4)));

#define VQ_D 64
#define VQ_K 512
#define VQ_NQ 131072
#define VQ_TOTAL 8388608
#define NCK 8            // staged chunks (4 tiles = 64 codes = 16 KB each)
#define TAU 8e-3f

typedef __attribute__((address_space(1))) void as1_void;
typedef __attribute__((address_space(3))) void as3_void;

__device__ __forceinline__ void gll16(const void* g, void* l) {
    // global -> LDS direct copy, 16 B per lane; LDS dest = wave-uniform base + lane*16
    __builtin_amdgcn_global_load_lds((as1_void*)(void*)g, (as3_void*)l, 16, 0, 0);
}
__device__ __forceinline__ void gll4(const void* g, void* l) {
    __builtin_amdgcn_global_load_lds((as1_void*)(void*)g, (as3_void*)l, 4, 0, 0);
}

__device__ __forceinline__ ushort bf16_rne(float f) {
    uint u = __builtin_bit_cast(uint, f);
    u += 0x7fffu + ((u >> 16) & 1u);
    return (ushort)(u >> 16);
}
__device__ __forceinline__ float bf16_to_f(ushort h) {
    uint u = ((uint)h) << 16;
    return __builtin_bit_cast(float, u);
}
// bf16-RNE leaving the result in the TOP 16 bits (for v_perm packing)
__device__ __forceinline__ uint rne_top(float r) {
    uint t = __builtin_bit_cast(uint, r);
    return t + 0x7fffu + ((t >> 16) & 1u);
}
// pack top16(a) as low ushort, top16(b) as high ushort: one v_perm_b32
__device__ __forceinline__ uint pack_hi16(uint a, uint b) {
    return __builtin_amdgcn_perm(b, a, 0x07060302u);
}

// ---- prep: w -> bf16 hi/lo in MFMA B-fragment order + fp32 norms + loss=0 ----
// (verbatim R10/R11/R13: 8 threads per code, 32 blocks)
__global__ __launch_bounds__(128) void vq_prep(const float* __restrict__ w,
                                               ushort* __restrict__ wfrag,
                                               float* __restrict__ wn,
                                               float* __restrict__ out) {
    if (blockIdx.x == 0 && threadIdx.x == 0) out[VQ_TOTAL] = 0.f;
    const int tid = threadIdx.x;
    const int k = (blockIdx.x << 4) + (tid >> 3);   // code index
    const int g = tid & 7;                          // granule: d in [g*8, g*8+8)
    const float4* row = (const float4*)(w + k * VQ_D);
    float4 a = row[2 * g], b4 = row[2 * g + 1];
    float v[8] = {a.x, a.y, a.z, a.w, b4.x, b4.y, b4.z, b4.w};
    ushort hi[8], lo[8];
    float nrm = 0.f;
#pragma unroll
    for (int j = 0; j < 8; ++j) {
        nrm = fmaf(v[j], v[j], nrm);
        hi[j] = bf16_rne(v[j]);
        lo[j] = bf16_rne(v[j] - bf16_to_f(hi[j]));
    }
    // sum ||.||^2 over the code's 8 granules (lanes k*8..k*8+7, same wave)
    nrm += __shfl_xor(nrm, 1, 64);
    nrm += __shfl_xor(nrm, 2, 64);
    nrm += __shfl_xor(nrm, 4, 64);
    if (g == 0) wn[k] = nrm;
    const int t = k >> 4, col = k & 15;
    const int quad = g & 3, fh = g >> 2;
    bf16x8* basez = (bf16x8*)wfrag + t * 256 + quad * 16 + col;
    basez[fh * 64]       = *(bf16x8*)hi;    // bh{fh}
    basez[(2 + fh) * 64] = *(bf16x8*)lo;    // bl{fh}
}

__global__ __launch_bounds__(512, 8) void vq_main(const float* __restrict__ in,
                                                  const float* __restrict__ w,
                                                  const ushort* __restrict__ wfrag,
                                                  const float* __restrict__ wng,
                                                  float* __restrict__ out) {
    __shared__ __align__(16) char bstage[2][16384];  // double-buffered B chunks
    __shared__ float wn_lds[VQ_K];
    __shared__ float xn_lds[128];
    __shared__ float best_lds[128], sec_lds[128];
    __shared__ int   bi_lds[128], si_lds[128];
    __shared__ double loss_lds[8];

    const int tid  = threadIdx.x;
    const int lane = tid & 63;
    const int wid  = tid >> 6;                 // 8 waves
    const int col  = lane & 15;
    const int quad = lane >> 4;
    const int n0  = blockIdx.x * 128;          // block's 128 queries (one image)
    const int b   = n0 >> 12;
    const int hw0 = n0 & 4095;
    const float* xg0 = in + (b << 18) + hw0;

    // ---- prologue staging: chunk 0 (16 KB) + wn (2 KB); overlaps A-prep ----
    {
        const char* gs = (const char*)wfrag + tid * 16;     // per-lane global src
        char* lb = &bstage[0][0] + wid * 1024;              // wave-uniform LDS base
        gll16(gs, lb);
        gll16(gs + 8192, lb + 8192);
        gll4(wng + tid, (char*)wn_lds + wid * 256);         // 512 floats
    }

    // ---- A fragments direct from global (x, bf16 hi/lo) + xnorm ----
    // 16 queries per wave: query = wid*16 + col; A[m=col][k=quad*8+j].
    bf16x8 ah0, ah1, al0, al1;
    {
        const float* xq = xg0 + wid * 16 + col;
        float sx = 0.f;
        uint AH0[4], AL0[4], AH1[4], AL1[4];
#pragma unroll
        for (int m = 0; m < 4; ++m) {          // bf16 pair m: j = 2m, 2m+1
            float a0 = xq[(quad * 8 + 2 * m) << 12];          // kstep0: d in [0,32)
            float b0 = xq[(quad * 8 + 2 * m + 1) << 12];
            float a1 = xq[(32 + quad * 8 + 2 * m) << 12];     // kstep1: d in [32,64)
            float b1 = xq[(32 + quad * 8 + 2 * m + 1) << 12];
            sx = fmaf(a0, a0, sx); sx = fmaf(b0, b0, sx);
            sx = fmaf(a1, a1, sx); sx = fmaf(b1, b1, sx);
            uint ua0 = __builtin_bit_cast(uint, a0), ub0 = __builtin_bit_cast(uint, b0);
            uint ua1 = __builtin_bit_cast(uint, a1), ub1 = __builtin_bit_cast(uint, b1);
            AH0[m] = pack_hi16(ua0, ub0);
            AH1[m] = pack_hi16(ua1, ub1);
            float ha0 = __builtin_bit_cast(float, ua0 & 0xFFFF0000u);
            float hb0 = __builtin_bit_cast(float, ub0 & 0xFFFF0000u);
            float ha1 = __builtin_bit_cast(float, ua1 & 0xFFFF0000u);
            float hb1 = __builtin_bit_cast(float, ub1 & 0xFFFF0000u);
            AL0[m] = pack_hi16(rne_top(a0 - ha0), rne_top(b0 - hb0));
            AL1[m] = pack_hi16(rne_top(a1 - ha1), rne_top(b1 - hb1));
        }
        ah0 = *(bf16x8*)AH0; al0 = *(bf16x8*)AL0;
        ah1 = *(bf16x8*)AH1; al1 = *(bf16x8*)AL1;
        sx += __shfl_xor(sx, 16, 64);                   // sum the 4 quads
        sx += __shfl_xor(sx, 32, 64);
        if (quad == 0) xn_lds[wid * 16 + col] = sx;
    }

    __syncthreads();   // drains prologue gll (vmcnt) + xn_lds writes

    // ---- K-loop: B from LDS double buffer; dist = fmaf(-2, acc, wn) ----
    float best[4], sec[4];
#pragma unroll
    for (int r = 0; r < 4; ++r) { best[r] = 3.0e38f; sec[r] = 3.0e38f; }

#pragma unroll 1
    for (int c = 0; c < NCK; ++c) {
        char* const bcur = &bstage[c & 1][0];
        if (c + 1 < NCK) {                      // prefetch next 16 KB chunk
            const char* gs = (const char*)wfrag + (c + 1) * 16384 + tid * 16;
            char* lb = &bstage[(c + 1) & 1][0] + wid * 1024;
            gll16(gs, lb);
            gll16(gs + 8192, lb + 8192);
        }
#pragma unroll
        for (int s = 0; s < 4; ++s) {           // four 16-code tiles per chunk
            const int t2 = 4 * c + s;
            const char* rb = bcur + s * 4096 + lane * 16;
            bf16x8 bh0 = *(const bf16x8*)(rb);
            bf16x8 bh1 = *(const bf16x8*)(rb + 1024);
            bf16x8 bl0 = *(const bf16x8*)(rb + 2048);
            bf16x8 bl1 = *(const bf16x8*)(rb + 3072);
            const float wnv = wn_lds[t2 * 16 + col];
            f32x4 acc = {0.f, 0.f, 0.f, 0.f};   // merged accumulator (R13)
            acc = __builtin_amdgcn_mfma_f32_16x16x32_bf16(ah0, bh0, acc, 0, 0, 0);
            acc = __builtin_amdgcn_mfma_f32_16x16x32_bf16(ah1, bh1, acc, 0, 0, 0);
            acc = __builtin_amdgcn_mfma_f32_16x16x32_bf16(ah0, bl0, acc, 0, 0, 0);
            acc = __builtin_amdgcn_mfma_f32_16x16x32_bf16(ah1, bl1, acc, 0, 0, 0);
            acc = __builtin_amdgcn_mfma_f32_16x16x32_bf16(al0, bh0, acc, 0, 0, 0);
            acc = __builtin_amdgcn_mfma_f32_16x16x32_bf16(al1, bh1, acc, 0, 0, 0);
#pragma unroll
            for (int j = 0; j < 4; ++j) {       // C: row(query)=quad*4+j, col=code
                float dist = fmaf(-2.f, acc[j], wnv);
                uint u = (__builtin_bit_cast(uint, dist) & 0xFFFFFFE0u)
                       | ((uint)t2 & 0x1Fu);    // fuses to v_bfi_b32
                float key = __builtin_bit_cast(float, u);
                // sec = median(best, sec, key) == fmax+fmin pair (verified R17/R18)
                sec[j]  = __builtin_amdgcn_fmed3f(best[j], sec[j], key);
                best[j] = fminf(best[j], key);
            }
        }
        __syncthreads();   // chunk c reads done; chunk c+1 staged
    }

    // ---- unpack packed keys -> (dist_class, global code idx) (R13 verbatim) ----
    float bD[4], sD[4];
    int bI[4], sI[4];
#pragma unroll
    for (int r = 0; r < 4; ++r) {
        uint ub = __builtin_bit_cast(uint, best[r]);
        uint us = __builtin_bit_cast(uint, sec[r]);
        bI[r] = (int)(ub & 31u) * 16 + col;
        sI[r] = (int)(us & 31u) * 16 + col;
        bD[r] = __builtin_bit_cast(float, ub & 0xFFFFFFE0u);
        sD[r] = __builtin_bit_cast(float, us & 0xFFFFFFE0u);
    }

    // ---- merge across 16 col-lanes (R13 verbatim) ----
#pragma unroll
    for (int off = 1; off < 16; off <<= 1) {
#pragma unroll
        for (int r = 0; r < 4; ++r) {
            float ob = __shfl_xor(bD[r], off, 64);
            float os = __shfl_xor(sD[r], off, 64);
            int   oi = __shfl_xor(bI[r], off, 64);
            int   oc = __shfl_xor(sI[r], off, 64);
            bool oWins = (ob < bD[r]) || (ob == bD[r] && oi < bI[r]);
            float nb  = oWins ? ob    : bD[r];
            int   ni  = oWins ? oi    : bI[r];
            float c1  = oWins ? bD[r] : ob;      // loser's best
            int   ci1 = oWins ? bI[r] : oi;
            float c2  = oWins ? os    : sD[r];   // winner's second
            int   ci2 = oWins ? oc    : sI[r];
            bool c1w = (c1 < c2) || (c1 == c2 && ci1 < ci2);
            sD[r] = c1w ? c1  : c2;
            sI[r] = c1w ? ci1 : ci2;
            bD[r] = nb; bI[r] = ni;
        }
    }
    if (col == 0) {
#pragma unroll
        for (int r = 0; r < 4; ++r) {           // q in block = wid*16 + quad*4 + r
            const int q = wid * 16 + quad * 4 + r;
            best_lds[q] = bD[r]; sec_lds[q] = sD[r];
            bi_lds[q] = bI[r];   si_lds[q] = sI[r];
        }
    }
    __syncthreads();

    // ---- epilogue: fp64 near-tie re-rank, 4 lanes per query + loss (R13 verbatim) ----
    {
        const int q = tid >> 2, part = tid & 3;   // lanes 4k..4k+3 share query q
        float cb = best_lds[q], cs = sec_lds[q];
        int cbi = bi_lds[q], csi = si_lds[q];
        double chosen = (double)cb;
        if (cs - cb < TAU) {
            const float* wb  = w + cbi * VQ_D + part * 16;
            const float* ws2 = w + csi * VQ_D + part * 16;
            const float* xqp = xg0 + q;
            double nb = 0.0, dotb = 0.0, ns = 0.0, dots = 0.0;
#pragma unroll
            for (int d0 = 0; d0 < 16; ++d0) {
                const int d = part * 16 + d0;
                double xv = (double)xqp[d << 12];
                double wbv = (double)wb[d0], wsv = (double)ws2[d0];
                nb = fma(wbv, wbv, nb); dotb = fma(xv, wbv, dotb);
                ns = fma(wsv, wsv, ns); dots = fma(xv, wsv, dots);
            }
            // combine the 4 partials (butterfly within the 4-lane group)
#pragma unroll
            for (int off = 1; off < 4; off <<= 1) {
                nb   += __shfl_xor(nb,   off, 64);
                dotb += __shfl_xor(dotb, off, 64);
                ns   += __shfl_xor(ns,   off, 64);
                dots += __shfl_xor(dots, off, 64);
            }
            double db = nb - 2.0 * dotb, ds = ns - 2.0 * dots;
            if (ds < db || (ds == db && csi < cbi)) { cbi = csi; chosen = ds; }
            else                                    { chosen = db; }
        }
        if (part == 0) bi_lds[q] = cbi;
        double lq = (part == 0) ? ((double)xn_lds[q] + chosen) : 0.0;
#pragma unroll
        for (int off = 32; off > 0; off >>= 1)
            lq += __shfl_down(lq, off, 64);
        if (lane == 0) loss_lds[wid] = lq;
    }
    __syncthreads();
    if (tid == 0) {
        double s = 0.0;
#pragma unroll
        for (int wv = 0; wv < 8; ++wv) s += loss_lds[wv];
        atomicAdd(out + VQ_TOTAL, (float)(s * (1.0 / (double)VQ_TOTAL)));
    }

    // ---- cooperative quantized write: 4 threads/query (R13 verbatim) ----
    {
        const int q = tid & 127, quarter = tid >> 7;  // quarter: d in [16*quarter, +16)
        const float4* wrow = (const float4*)(w + bi_lds[q] * VQ_D) + quarter * 4;
        float* op = out + (b << 18) + hw0 + q;
#pragma unroll
        for (int u = 0; u < 4; ++u) {
            float4 v = wrow[u];
            const int d = quarter * 16 + 4 * u;
            op[(d + 0) << 12] = v.x;
            op[(d + 1) << 12] = v.y;
            op[(d + 2) << 12] = v.z;
            op[(d + 3) << 12] = v.w;
        }
    }
}

extern "C" void kernel_launch(void* const* d_in, const int* in_sizes, int n_in,
                              void* d_out, int out_size, void* d_ws, size_t ws_size,
                              hipStream_t stream) {
    const float* in = (const float*)d_in[0];
    const float* w  = (const float*)d_in[1];
    float* out = (float*)d_out;

    ushort* wfrag = (ushort*)d_ws;                    // 512*128 ushort = 128 KB
    float*  wn    = (float*)((char*)d_ws + 131072);   // 512 floats

    vq_prep<<<32, 128, 0, stream>>>(w, wfrag, wn, out);   // also zeroes loss cell
    vq_main<<<VQ_NQ / 128, 512, 0, stream>>>(in, w, wfrag, wn, out);
}